// Round 4
// baseline (888.604 us; speedup 1.0000x reference)
//
#include <hip/hip_runtime.h>

constexpr int F_IN  = 512;
constexpr int HID   = 16;
constexpr int NCLS  = 40;
constexpr int CHUNK = 4096;   // edges per count/scatter block
constexpr int BMAX  = 800;    // max buckets (N=100000 -> NB=782)

// ---- Pass A: per-chunk histogram of dst buckets (LDS atomics only) ----
__global__ void k_count(const int* __restrict__ dst, int* __restrict__ counts,
                        int E, int NB, int NBLKp) {
  __shared__ int hist[BMAX];
  int t = threadIdx.x;
  for (int b = t; b < BMAX; b += 256) hist[b] = 0;
  __syncthreads();
  int base = blockIdx.x * CHUNK;
  for (int i = 0; i < CHUNK; i += 256) {
    int e = base + i + t;
    if (e < E) atomicAdd(&hist[dst[e] >> 7], 1);
  }
  __syncthreads();
  for (int b = t; b < NB; b += 256) counts[b * NBLKp + blockIdx.x] = hist[b];
}

// ---- scan over counts (bucket-major), 3 stages, in-place ----
__global__ void k_scanA(const int* __restrict__ a, int* __restrict__ bsum) {
  __shared__ int sd[256];
  int t = threadIdx.x;
  int4 v = reinterpret_cast<const int4*>(a)[blockIdx.x * 256 + t];
  sd[t] = v.x + v.y + v.z + v.w;
  __syncthreads();
  for (int off = 128; off > 0; off >>= 1) {
    if (t < off) sd[t] += sd[t + off];
    __syncthreads();
  }
  if (!t) bsum[blockIdx.x] = sd[0];
}

__global__ void k_scanB(int* __restrict__ bsum, int nb) {
  __shared__ int sd[1024];
  int t = threadIdx.x;
  int v = (t < nb) ? bsum[t] : 0;
  sd[t] = v;
  __syncthreads();
  for (int off = 1; off < 1024; off <<= 1) {
    int add = (t >= off) ? sd[t - off] : 0;
    __syncthreads();
    sd[t] += add;
    __syncthreads();
  }
  if (t < nb) bsum[t] = sd[t] - v;  // exclusive
}

__global__ void k_scanC(int* __restrict__ a, const int* __restrict__ bsum) {
  __shared__ int sd[256];
  int t = threadIdx.x;
  int4 v = reinterpret_cast<int4*>(a)[blockIdx.x * 256 + t];
  int ts = v.x + v.y + v.z + v.w;
  sd[t] = ts;
  __syncthreads();
  for (int off = 1; off < 256; off <<= 1) {
    int add = (t >= off) ? sd[t - off] : 0;
    __syncthreads();
    sd[t] += add;
    __syncthreads();
  }
  int pre = bsum[blockIdx.x] + sd[t] - ts;
  int4 w;
  w.x = pre; w.y = pre + v.x; w.z = w.y + v.y; w.w = w.z + v.z;
  reinterpret_cast<int4*>(a)[blockIdx.x * 256 + t] = w;
}

// ---- Pass B: scatter edges into bucket-sorted payload (LDS cursors only) ----
__global__ void k_scatter(const int* __restrict__ src, const int* __restrict__ dst,
                          const float* __restrict__ ew, const int* __restrict__ counts,
                          uint2* __restrict__ payload, int E, int NB, int NBLKp) {
  __shared__ int cur[BMAX];
  int t = threadIdx.x;
  for (int b = t; b < NB; b += 256) cur[b] = counts[b * NBLKp + blockIdx.x];
  __syncthreads();
  int base = blockIdx.x * CHUNK;
  for (int i = 0; i < CHUNK; i += 256) {
    int e = base + i + t;
    if (e < E) {
      int s = src[e], d = dst[e];
      float w = ew[e];
      int pos = atomicAdd(&cur[d >> 7], 1);
      payload[pos] = make_uint2(((unsigned)s << 7) | (unsigned)(d & 127),
                                __float_as_uint(w));
    }
  }
}

// ---- per-bucket degree -> dis = rsqrt(1 + sum ew) ; 512 threads ----
__global__ void k_degb(const uint2* __restrict__ payload, const int* __restrict__ counts,
                       float* __restrict__ dis, int N, int NBLKp) {
  __shared__ float dg[128];
  int t = threadIdx.x;
  if (t < 128) dg[t] = 1.0f;  // self-loop weight
  __syncthreads();
  int beg = counts[blockIdx.x * NBLKp], end = counts[(blockIdx.x + 1) * NBLKp];
  int e = beg + t;
  for (; e + 512 < end; e += 1024) {
    uint2 p0 = payload[e];
    uint2 p1 = payload[e + 512];
    atomicAdd(&dg[p0.x & 127], __uint_as_float(p0.y));
    atomicAdd(&dg[p1.x & 127], __uint_as_float(p1.y));
  }
  if (e < end) {
    uint2 p = payload[e];
    atomicAdd(&dg[p.x & 127], __uint_as_float(p.y));
  }
  __syncthreads();
  int n = blockIdx.x * 128 + t;
  if (t < 128 && n < N) dis[n] = rsqrtf(dg[t]);
}

// ---- h1' = (x @ W1) * dis[n] ----
__global__ void k_gemm1(const float* __restrict__ x, const float* __restrict__ W1,
                        const float* __restrict__ dis, float* __restrict__ h1, int N) {
  int n = blockIdx.x * blockDim.x + threadIdx.x;
  if (n >= N) return;
  const float* xr = x + (size_t)n * F_IN;
  float acc[HID];
#pragma unroll
  for (int j = 0; j < HID; ++j) acc[j] = 0.0f;
  for (int k = 0; k < F_IN; k += 16) {
    float4 a0 = *reinterpret_cast<const float4*>(xr + k);
    float4 a1 = *reinterpret_cast<const float4*>(xr + k + 4);
    float4 a2 = *reinterpret_cast<const float4*>(xr + k + 8);
    float4 a3 = *reinterpret_cast<const float4*>(xr + k + 12);
    float xv[16] = {a0.x, a0.y, a0.z, a0.w, a1.x, a1.y, a1.z, a1.w,
                    a2.x, a2.y, a2.z, a2.w, a3.x, a3.y, a3.z, a3.w};
#pragma unroll
    for (int kk = 0; kk < 16; ++kk) {
      float xx = xv[kk];
      const float* wr = W1 + (size_t)(k + kk) * HID;
#pragma unroll
      for (int j = 0; j < HID; ++j) acc[j] = fmaf(xx, wr[j], acc[j]);
    }
  }
  float di = dis[n];
  float* hr = h1 + (size_t)n * HID;
#pragma unroll
  for (int j = 0; j < HID; ++j) hr[j] = acc[j] * di;
}

// ---- per-bucket aggregation, 512 threads (8 waves), unroll-2.
//      LAYER1: out = relu((acc+h')*dis+b1)*dis   LAYER2: out = (acc+h')*dis ----
template <int LAYER>
__global__ void __launch_bounds__(512, 2)
k_aggb(const uint2* __restrict__ payload, const int* __restrict__ counts,
       const float* __restrict__ h, const float* __restrict__ dis,
       const float* __restrict__ b1, float* __restrict__ outp,
       int N, int NBLKp) {
  __shared__ float acc[128 * HID];
  int t = threadIdx.x;
  for (int i = t; i < 128 * HID; i += 512) acc[i] = 0.0f;
  __syncthreads();
  int beg = counts[blockIdx.x * NBLKp], end = counts[(blockIdx.x + 1) * NBLKp];
  int j = t & 15;
  int e = beg + (t >> 4);  // 32 groups of 16 lanes, stride 32
  for (; e + 32 < end; e += 64) {
    uint2 p0 = payload[e];
    uint2 p1 = payload[e + 32];
    float v0 = h[((size_t)(p0.x >> 7) << 4) + j] * __uint_as_float(p0.y);
    float v1 = h[((size_t)(p1.x >> 7) << 4) + j] * __uint_as_float(p1.y);
    atomicAdd(&acc[(int)(p0.x & 127) * HID + j], v0);
    atomicAdd(&acc[(int)(p1.x & 127) * HID + j], v1);
  }
  if (e < end) {
    uint2 p = payload[e];
    atomicAdd(&acc[(int)(p.x & 127) * HID + j],
              h[((size_t)(p.x >> 7) << 4) + j] * __uint_as_float(p.y));
  }
  __syncthreads();
  int base = blockIdx.x * 128;
  for (int i = t; i < 128 * HID; i += 512) {
    int n = base + (i >> 4);
    if (n < N) {
      int jj = i & 15;
      float di = dis[n];
      float v = (acc[i] + h[(size_t)n * HID + jj]) * di;
      if (LAYER == 1) {
        v = fmaxf(v + b1[jj], 0.0f) * di;
      }
      outp[(size_t)n * HID + jj] = v;
    }
  }
}

// ---- out = log_softmax(g @ W2 + b2), thread-per-node ----
__global__ void k_out(const float* __restrict__ g, const float* __restrict__ W2,
                      const float* __restrict__ b2, float* __restrict__ out, int N) {
  int n = blockIdx.x * blockDim.x + threadIdx.x;
  if (n >= N) return;
  float gv[HID];
#pragma unroll
  for (int j = 0; j < HID; ++j) gv[j] = g[(size_t)n * HID + j];
  float o[NCLS];
#pragma unroll
  for (int c = 0; c < NCLS; ++c) o[c] = b2[c];
#pragma unroll
  for (int j = 0; j < HID; ++j) {
    float gj = gv[j];
    const float* wr = W2 + (size_t)j * NCLS;
#pragma unroll
    for (int c = 0; c < NCLS; ++c) o[c] = fmaf(gj, wr[c], o[c]);
  }
  float m = o[0];
#pragma unroll
  for (int c = 1; c < NCLS; ++c) m = fmaxf(m, o[c]);
  float ss = 0.0f;
#pragma unroll
  for (int c = 0; c < NCLS; ++c) ss += expf(o[c] - m);
  float lse = m + logf(ss);
  float* orow = out + (size_t)n * NCLS;
#pragma unroll
  for (int c = 0; c < NCLS; ++c) orow[c] = o[c] - lse;
}

extern "C" void kernel_launch(void* const* d_in, const int* in_sizes, int n_in,
                              void* d_out, int out_size, void* d_ws, size_t ws_size,
                              hipStream_t stream) {
  const float* x  = (const float*)d_in[0];
  const int*   ei = (const int*)d_in[1];
  const float* ew = (const float*)d_in[2];
  const float* W1 = (const float*)d_in[3];
  const float* b1 = (const float*)d_in[4];
  const float* W2 = (const float*)d_in[5];
  const float* b2 = (const float*)d_in[6];
  float* out = (float*)d_out;

  const int N = in_sizes[0] / F_IN;   // 100000
  const int E = in_sizes[2];          // 3200000
  const int* src = ei;
  const int* dst = ei + E;

  const int NB    = (N + 127) >> 7;            // 782 buckets (<= BMAX)
  const int NBLK  = (E + CHUNK - 1) / CHUNK;   // 782 chunks
  const int NBLKp = (NBLK + 31) & ~31;         // 800
  const long long SCT = (long long)NB * NBLKp + 1;
  const int Npad  = (int)((SCT + 1023) & ~1023LL);
  const int nbScan = Npad / 1024;

  // ws layout (4B words): counts[Npad] | bsum[1024] | dis | h1[N*16] | h2[N*16] | payload[2*E]
  int* counts = (int*)d_ws;
  int* bsum   = counts + Npad;
  float* dis  = (float*)(bsum + 1024);
  float* h1   = dis + ((N + 255) & ~255);
  float* h2   = h1 + (size_t)N * HID;
  uint2* payload = (uint2*)(h2 + (size_t)N * HID);
  float* g = h1;  // h1 dead after layer-1 aggregation

  hipMemsetAsync(counts, 0, (size_t)Npad * sizeof(int), stream);
  k_count<<<NBLK, 256, 0, stream>>>(dst, counts, E, NB, NBLKp);
  k_scanA<<<nbScan, 256, 0, stream>>>(counts, bsum);
  k_scanB<<<1, 1024, 0, stream>>>(bsum, nbScan);
  k_scanC<<<nbScan, 256, 0, stream>>>(counts, bsum);
  k_scatter<<<NBLK, 256, 0, stream>>>(src, dst, ew, counts, payload, E, NB, NBLKp);
  k_degb<<<NB, 512, 0, stream>>>(payload, counts, dis, N, NBLKp);
  k_gemm1<<<(N + 255) / 256, 256, 0, stream>>>(x, W1, dis, h1, N);
  k_aggb<1><<<NB, 512, 0, stream>>>(payload, counts, h1, dis, b1, h2, N, NBLKp);
  k_aggb<2><<<NB, 512, 0, stream>>>(payload, counts, h2, dis, nullptr, g, N, NBLKp);
  k_out<<<(N + 255) / 256, 256, 0, stream>>>(g, W2, b2, out, N);
}

// Round 5
// 878.427 us; speedup vs baseline: 1.0116x; 1.0116x over previous
//
#include <hip/hip_runtime.h>

constexpr int F_IN  = 512;
constexpr int HID   = 16;
constexpr int NCLS  = 40;
constexpr int CHUNK = 4096;   // edges per count/scatter block
constexpr int BMAX  = 800;    // max buckets (N=100000 -> NB=782)
constexpr int APAD  = 17;     // acc row stride (17 odd -> uniform bank spread)

// ---- Pass A: per-chunk histogram of dst buckets (LDS atomics only) ----
__global__ void k_count(const int* __restrict__ dst, int* __restrict__ counts,
                        int E, int NB, int NBLKp) {
  __shared__ int hist[BMAX];
  int t = threadIdx.x;
  for (int b = t; b < BMAX; b += 256) hist[b] = 0;
  __syncthreads();
  int base = blockIdx.x * CHUNK;
  for (int i = 0; i < CHUNK; i += 256) {
    int e = base + i + t;
    if (e < E) atomicAdd(&hist[dst[e] >> 7], 1);
  }
  __syncthreads();
  for (int b = t; b < NB; b += 256) counts[b * NBLKp + blockIdx.x] = hist[b];
}

// ---- scan over counts (bucket-major), 3 stages, in-place ----
__global__ void k_scanA(const int* __restrict__ a, int* __restrict__ bsum) {
  __shared__ int sd[256];
  int t = threadIdx.x;
  int4 v = reinterpret_cast<const int4*>(a)[blockIdx.x * 256 + t];
  sd[t] = v.x + v.y + v.z + v.w;
  __syncthreads();
  for (int off = 128; off > 0; off >>= 1) {
    if (t < off) sd[t] += sd[t + off];
    __syncthreads();
  }
  if (!t) bsum[blockIdx.x] = sd[0];
}

__global__ void k_scanB(int* __restrict__ bsum, int nb) {
  __shared__ int sd[1024];
  int t = threadIdx.x;
  int v = (t < nb) ? bsum[t] : 0;
  sd[t] = v;
  __syncthreads();
  for (int off = 1; off < 1024; off <<= 1) {
    int add = (t >= off) ? sd[t - off] : 0;
    __syncthreads();
    sd[t] += add;
    __syncthreads();
  }
  if (t < nb) bsum[t] = sd[t] - v;  // exclusive
}

__global__ void k_scanC(int* __restrict__ a, const int* __restrict__ bsum) {
  __shared__ int sd[256];
  int t = threadIdx.x;
  int4 v = reinterpret_cast<int4*>(a)[blockIdx.x * 256 + t];
  int ts = v.x + v.y + v.z + v.w;
  sd[t] = ts;
  __syncthreads();
  for (int off = 1; off < 256; off <<= 1) {
    int add = (t >= off) ? sd[t - off] : 0;
    __syncthreads();
    sd[t] += add;
    __syncthreads();
  }
  int pre = bsum[blockIdx.x] + sd[t] - ts;
  int4 w;
  w.x = pre; w.y = pre + v.x; w.z = w.y + v.y; w.w = w.z + v.z;
  reinterpret_cast<int4*>(a)[blockIdx.x * 256 + t] = w;
}

// ---- Pass B: scatter edges into bucket-sorted payload (LDS cursors only) ----
__global__ void k_scatter(const int* __restrict__ src, const int* __restrict__ dst,
                          const float* __restrict__ ew, const int* __restrict__ counts,
                          uint2* __restrict__ payload, int E, int NB, int NBLKp) {
  __shared__ int cur[BMAX];
  int t = threadIdx.x;
  for (int b = t; b < NB; b += 256) cur[b] = counts[b * NBLKp + blockIdx.x];
  __syncthreads();
  int base = blockIdx.x * CHUNK;
  for (int i = 0; i < CHUNK; i += 256) {
    int e = base + i + t;
    if (e < E) {
      int s = src[e], d = dst[e];
      float w = ew[e];
      int pos = atomicAdd(&cur[d >> 7], 1);
      payload[pos] = make_uint2(((unsigned)s << 7) | (unsigned)(d & 127),
                                __float_as_uint(w));
    }
  }
}

// ---- per-bucket degree -> dis = rsqrt(1 + sum ew) ; 512 threads ----
__global__ void k_degb(const uint2* __restrict__ payload, const int* __restrict__ counts,
                       float* __restrict__ dis, int N, int NBLKp) {
  __shared__ float dg[128];
  int t = threadIdx.x;
  if (t < 128) dg[t] = 1.0f;  // self-loop weight
  __syncthreads();
  int beg = counts[blockIdx.x * NBLKp], end = counts[(blockIdx.x + 1) * NBLKp];
  int e = beg + t;
  for (; e + 512 < end; e += 1024) {
    uint2 p0 = payload[e];
    uint2 p1 = payload[e + 512];
    atomicAdd(&dg[p0.x & 127], __uint_as_float(p0.y));
    atomicAdd(&dg[p1.x & 127], __uint_as_float(p1.y));
  }
  if (e < end) {
    uint2 p = payload[e];
    atomicAdd(&dg[p.x & 127], __uint_as_float(p.y));
  }
  __syncthreads();
  int n = blockIdx.x * 128 + t;
  if (t < 128 && n < N) dis[n] = rsqrtf(dg[t]);
}

// ---- h1' = (x @ W1) * dis[n] ----
__global__ void k_gemm1(const float* __restrict__ x, const float* __restrict__ W1,
                        const float* __restrict__ dis, float* __restrict__ h1, int N) {
  int n = blockIdx.x * blockDim.x + threadIdx.x;
  if (n >= N) return;
  const float* xr = x + (size_t)n * F_IN;
  float acc[HID];
#pragma unroll
  for (int j = 0; j < HID; ++j) acc[j] = 0.0f;
  for (int k = 0; k < F_IN; k += 16) {
    float4 a0 = *reinterpret_cast<const float4*>(xr + k);
    float4 a1 = *reinterpret_cast<const float4*>(xr + k + 4);
    float4 a2 = *reinterpret_cast<const float4*>(xr + k + 8);
    float4 a3 = *reinterpret_cast<const float4*>(xr + k + 12);
    float xv[16] = {a0.x, a0.y, a0.z, a0.w, a1.x, a1.y, a1.z, a1.w,
                    a2.x, a2.y, a2.z, a2.w, a3.x, a3.y, a3.z, a3.w};
#pragma unroll
    for (int kk = 0; kk < 16; ++kk) {
      float xx = xv[kk];
      const float* wr = W1 + (size_t)(k + kk) * HID;
#pragma unroll
      for (int j = 0; j < HID; ++j) acc[j] = fmaf(xx, wr[j], acc[j]);
    }
  }
  float di = dis[n];
  float* hr = h1 + (size_t)n * HID;
#pragma unroll
  for (int j = 0; j < HID; ++j) hr[j] = acc[j] * di;
}

// 16 ds_add_f32 for one edge's row, compile-time feature indices
__device__ __forceinline__ void scatter_row(float* __restrict__ acc, int b,
                                            float4 q0, float4 q1, float4 q2, float4 q3,
                                            float w) {
  atomicAdd(&acc[b + 0],  q0.x * w); atomicAdd(&acc[b + 1],  q0.y * w);
  atomicAdd(&acc[b + 2],  q0.z * w); atomicAdd(&acc[b + 3],  q0.w * w);
  atomicAdd(&acc[b + 4],  q1.x * w); atomicAdd(&acc[b + 5],  q1.y * w);
  atomicAdd(&acc[b + 6],  q1.z * w); atomicAdd(&acc[b + 7],  q1.w * w);
  atomicAdd(&acc[b + 8],  q2.x * w); atomicAdd(&acc[b + 9],  q2.y * w);
  atomicAdd(&acc[b + 10], q2.z * w); atomicAdd(&acc[b + 11], q2.w * w);
  atomicAdd(&acc[b + 12], q3.x * w); atomicAdd(&acc[b + 13], q3.y * w);
  atomicAdd(&acc[b + 14], q3.z * w); atomicAdd(&acc[b + 15], q3.w * w);
}

// ---- per-bucket aggregation: ONE EDGE PER LANE, 4xfloat4 row gather, unroll 2.
//      LAYER1: out = relu((acc+h')*dis+b1)*dis   LAYER2: out = (acc+h')*dis ----
template <int LAYER>
__global__ void k_aggb(const uint2* __restrict__ payload, const int* __restrict__ counts,
                       const float* __restrict__ h, const float* __restrict__ dis,
                       const float* __restrict__ b1, float* __restrict__ outp,
                       int N, int NBLKp) {
  __shared__ float acc[128 * APAD];
  int t = threadIdx.x;
  for (int i = t; i < 128 * APAD; i += 256) acc[i] = 0.0f;
  __syncthreads();
  int beg = counts[blockIdx.x * NBLKp], end = counts[(blockIdx.x + 1) * NBLKp];
  int e = beg + t;
  for (; e + 256 < end; e += 512) {
    uint2 p0 = payload[e];
    uint2 p1 = payload[e + 256];
    const float4* r0 = reinterpret_cast<const float4*>(h) + ((size_t)(p0.x >> 7) << 2);
    const float4* r1 = reinterpret_cast<const float4*>(h) + ((size_t)(p1.x >> 7) << 2);
    float4 a0 = r0[0], a1 = r0[1], a2 = r0[2], a3 = r0[3];
    float4 c0 = r1[0], c1 = r1[1], c2 = r1[2], c3 = r1[3];
    float w0 = __uint_as_float(p0.y), w1 = __uint_as_float(p1.y);
    scatter_row(acc, (int)(p0.x & 127) * APAD, a0, a1, a2, a3, w0);
    scatter_row(acc, (int)(p1.x & 127) * APAD, c0, c1, c2, c3, w1);
  }
  for (; e < end; e += 256) {
    uint2 p = payload[e];
    const float4* r = reinterpret_cast<const float4*>(h) + ((size_t)(p.x >> 7) << 2);
    float4 a0 = r[0], a1 = r[1], a2 = r[2], a3 = r[3];
    scatter_row(acc, (int)(p.x & 127) * APAD, a0, a1, a2, a3, __uint_as_float(p.y));
  }
  __syncthreads();
  int base = blockIdx.x * 128;
  for (int i = t; i < 128 * HID; i += 256) {
    int nl = i >> 4, jj = i & 15;
    int n = base + nl;
    if (n < N) {
      float di = dis[n];
      float v = (acc[nl * APAD + jj] + h[(size_t)n * HID + jj]) * di;
      if (LAYER == 1) {
        v = fmaxf(v + b1[jj], 0.0f) * di;
      }
      outp[(size_t)n * HID + jj] = v;
    }
  }
}

// ---- out = log_softmax(g @ W2 + b2), thread-per-node ----
__global__ void k_out(const float* __restrict__ g, const float* __restrict__ W2,
                      const float* __restrict__ b2, float* __restrict__ out, int N) {
  int n = blockIdx.x * blockDim.x + threadIdx.x;
  if (n >= N) return;
  float gv[HID];
#pragma unroll
  for (int j = 0; j < HID; ++j) gv[j] = g[(size_t)n * HID + j];
  float o[NCLS];
#pragma unroll
  for (int c = 0; c < NCLS; ++c) o[c] = b2[c];
#pragma unroll
  for (int j = 0; j < HID; ++j) {
    float gj = gv[j];
    const float* wr = W2 + (size_t)j * NCLS;
#pragma unroll
    for (int c = 0; c < NCLS; ++c) o[c] = fmaf(gj, wr[c], o[c]);
  }
  float m = o[0];
#pragma unroll
  for (int c = 1; c < NCLS; ++c) m = fmaxf(m, o[c]);
  float ss = 0.0f;
#pragma unroll
  for (int c = 0; c < NCLS; ++c) ss += expf(o[c] - m);
  float lse = m + logf(ss);
  float* orow = out + (size_t)n * NCLS;
#pragma unroll
  for (int c = 0; c < NCLS; ++c) orow[c] = o[c] - lse;
}

extern "C" void kernel_launch(void* const* d_in, const int* in_sizes, int n_in,
                              void* d_out, int out_size, void* d_ws, size_t ws_size,
                              hipStream_t stream) {
  const float* x  = (const float*)d_in[0];
  const int*   ei = (const int*)d_in[1];
  const float* ew = (const float*)d_in[2];
  const float* W1 = (const float*)d_in[3];
  const float* b1 = (const float*)d_in[4];
  const float* W2 = (const float*)d_in[5];
  const float* b2 = (const float*)d_in[6];
  float* out = (float*)d_out;

  const int N = in_sizes[0] / F_IN;   // 100000
  const int E = in_sizes[2];          // 3200000
  const int* src = ei;
  const int* dst = ei + E;

  const int NB    = (N + 127) >> 7;            // 782 buckets (<= BMAX)
  const int NBLK  = (E + CHUNK - 1) / CHUNK;   // 782 chunks
  const int NBLKp = (NBLK + 31) & ~31;         // 800
  const long long SCT = (long long)NB * NBLKp + 1;
  const int Npad  = (int)((SCT + 1023) & ~1023LL);
  const int nbScan = Npad / 1024;

  // ws layout (4B words): counts[Npad] | bsum[1024] | dis | h1[N*16] | h2[N*16] | payload[2*E]
  int* counts = (int*)d_ws;
  int* bsum   = counts + Npad;
  float* dis  = (float*)(bsum + 1024);
  float* h1   = dis + ((N + 255) & ~255);
  float* h2   = h1 + (size_t)N * HID;
  uint2* payload = (uint2*)(h2 + (size_t)N * HID);
  float* g = h1;  // h1 dead after layer-1 aggregation

  hipMemsetAsync(counts, 0, (size_t)Npad * sizeof(int), stream);
  k_count<<<NBLK, 256, 0, stream>>>(dst, counts, E, NB, NBLKp);
  k_scanA<<<nbScan, 256, 0, stream>>>(counts, bsum);
  k_scanB<<<1, 1024, 0, stream>>>(bsum, nbScan);
  k_scanC<<<nbScan, 256, 0, stream>>>(counts, bsum);
  k_scatter<<<NBLK, 256, 0, stream>>>(src, dst, ew, counts, payload, E, NB, NBLKp);
  k_degb<<<NB, 512, 0, stream>>>(payload, counts, dis, N, NBLKp);
  k_gemm1<<<(N + 255) / 256, 256, 0, stream>>>(x, W1, dis, h1, N);
  k_aggb<1><<<NB, 256, 0, stream>>>(payload, counts, h1, dis, b1, h2, N, NBLKp);
  k_aggb<2><<<NB, 256, 0, stream>>>(payload, counts, h2, dis, nullptr, g, N, NBLKp);
  k_out<<<(N + 255) / 256, 256, 0, stream>>>(g, W2, b2, out, N);
}

// Round 6
// 324.614 us; speedup vs baseline: 2.7374x; 2.7061x over previous
//
#include <hip/hip_runtime.h>
#include <hip/hip_bf16.h>

constexpr int F_IN  = 512;
constexpr int HID   = 16;
constexpr int NCLS  = 40;
constexpr int CHUNK = 4096;   // edges per count/scatter block
constexpr int BMAX  = 800;    // max buckets (N=100000 -> NB=782)
constexpr int SMAX  = 6144;   // max edges per bucket (mean 4096, sd 64 -> 32 sigma)

// ---- Pass A: per-chunk histogram of dst buckets (LDS atomics only) ----
__global__ void k_count(const int* __restrict__ dst, int* __restrict__ counts,
                        int E, int NB, int NBLKp) {
  __shared__ int hist[BMAX];
  int t = threadIdx.x;
  for (int b = t; b < BMAX; b += 256) hist[b] = 0;
  __syncthreads();
  int base = blockIdx.x * CHUNK;
  for (int i = 0; i < CHUNK; i += 256) {
    int e = base + i + t;
    if (e < E) atomicAdd(&hist[dst[e] >> 7], 1);
  }
  __syncthreads();
  for (int b = t; b < NB; b += 256) counts[b * NBLKp + blockIdx.x] = hist[b];
}

// ---- scan over counts (bucket-major), 3 stages, in-place ----
__global__ void k_scanA(const int* __restrict__ a, int* __restrict__ bsum) {
  __shared__ int sd[256];
  int t = threadIdx.x;
  int4 v = reinterpret_cast<const int4*>(a)[blockIdx.x * 256 + t];
  sd[t] = v.x + v.y + v.z + v.w;
  __syncthreads();
  for (int off = 128; off > 0; off >>= 1) {
    if (t < off) sd[t] += sd[t + off];
    __syncthreads();
  }
  if (!t) bsum[blockIdx.x] = sd[0];
}

__global__ void k_scanB(int* __restrict__ bsum, int nb) {
  __shared__ int sd[1024];
  int t = threadIdx.x;
  int v = (t < nb) ? bsum[t] : 0;
  sd[t] = v;
  __syncthreads();
  for (int off = 1; off < 1024; off <<= 1) {
    int add = (t >= off) ? sd[t - off] : 0;
    __syncthreads();
    sd[t] += add;
    __syncthreads();
  }
  if (t < nb) bsum[t] = sd[t] - v;  // exclusive
}

__global__ void k_scanC(int* __restrict__ a, const int* __restrict__ bsum) {
  __shared__ int sd[256];
  int t = threadIdx.x;
  int4 v = reinterpret_cast<int4*>(a)[blockIdx.x * 256 + t];
  int ts = v.x + v.y + v.z + v.w;
  sd[t] = ts;
  __syncthreads();
  for (int off = 1; off < 256; off <<= 1) {
    int add = (t >= off) ? sd[t - off] : 0;
    __syncthreads();
    sd[t] += add;
    __syncthreads();
  }
  int pre = bsum[blockIdx.x] + sd[t] - ts;
  int4 w;
  w.x = pre; w.y = pre + v.x; w.z = w.y + v.y; w.w = w.z + v.z;
  reinterpret_cast<int4*>(a)[blockIdx.x * 256 + t] = w;
}

// ---- Pass B: scatter edges into bucket-sorted payload (LDS cursors only) ----
__global__ void k_scatter(const int* __restrict__ src, const int* __restrict__ dst,
                          const float* __restrict__ ew, const int* __restrict__ counts,
                          uint2* __restrict__ payload, int E, int NB, int NBLKp) {
  __shared__ int cur[BMAX];
  int t = threadIdx.x;
  for (int b = t; b < NB; b += 256) cur[b] = counts[b * NBLKp + blockIdx.x];
  __syncthreads();
  int base = blockIdx.x * CHUNK;
  for (int i = 0; i < CHUNK; i += 256) {
    int e = base + i + t;
    if (e < E) {
      int s = src[e], d = dst[e];
      float w = ew[e];
      int pos = atomicAdd(&cur[d >> 7], 1);
      payload[pos] = make_uint2(((unsigned)s << 7) | (unsigned)(d & 127),
                                __float_as_uint(w));
    }
  }
}

// ---- Pass C: per-bucket in-place counting sort by dst-low-7 -> per-node CSR.
//      Also computes deg/dis (folds old k_degb). LDS only; no global atomics. ----
__global__ void __launch_bounds__(256)
k_sortb(uint2* __restrict__ payload, const int* __restrict__ counts,
        int* __restrict__ rs, float* __restrict__ dis, int N, int NBLKp) {
  __shared__ uint2 ebuf[SMAX];
  __shared__ int hcnt[128];
  __shared__ int sc[128];
  __shared__ float dgs[128];
  int t = threadIdx.x;
  if (t < 128) { hcnt[t] = 0; dgs[t] = 1.0f; }
  __syncthreads();
  int beg = counts[blockIdx.x * NBLKp];
  int end = counts[(blockIdx.x + 1) * NBLKp];
  int sz = end - beg;
  for (int i = t; i < sz; i += 256) {
    uint2 p = payload[beg + i];
    ebuf[i] = p;
    atomicAdd(&hcnt[p.x & 127], 1);
    atomicAdd(&dgs[p.x & 127], __uint_as_float(p.y));
  }
  __syncthreads();
  int v = (t < 128) ? hcnt[t] : 0;
  if (t < 128) sc[t] = v;
  __syncthreads();
  for (int off = 1; off < 128; off <<= 1) {
    int add = (t < 128 && t >= off) ? sc[t - off] : 0;
    __syncthreads();
    if (t < 128) sc[t] += add;
    __syncthreads();
  }
  int base = blockIdx.x * 128;
  if (t < 128) {
    int st = sc[t] - v;        // exclusive prefix within bucket
    hcnt[t] = st;              // reuse as relative cursor
    rs[base + t] = beg + st;
    int n = base + t;
    if (n < N) dis[n] = rsqrtf(dgs[t]);
  }
  if (t == 0) rs[base + 128] = end;  // overlaps next bucket's start write: same value
  __syncthreads();
  for (int i = t; i < sz; i += 256) {
    uint2 p = ebuf[i];
    int pos = beg + atomicAdd(&hcnt[p.x & 127], 1);
    payload[pos] = make_uint2(p.x >> 7, p.y);   // store plain src index + weight
  }
}

__device__ __forceinline__ float blo(unsigned u) { return __uint_as_float(u << 16); }
__device__ __forceinline__ float bhi(unsigned u) { return __uint_as_float(u & 0xffff0000u); }
__device__ __forceinline__ unsigned pack2(float lo, float hi) {
  __hip_bfloat16 l = __float2bfloat16(lo), h = __float2bfloat16(hi);
  unsigned short ul = *reinterpret_cast<unsigned short*>(&l);
  unsigned short uh = *reinterpret_cast<unsigned short*>(&h);
  return (unsigned)ul | ((unsigned)uh << 16);
}

// ---- h1' = (x @ W1) * dis[n], stored as bf16 rows (32B) ----
__global__ void k_gemm1(const float* __restrict__ x, const float* __restrict__ W1,
                        const float* __restrict__ dis, uint4* __restrict__ hb1, int N) {
  int n = blockIdx.x * blockDim.x + threadIdx.x;
  if (n >= N) return;
  const float* xr = x + (size_t)n * F_IN;
  float acc[HID];
#pragma unroll
  for (int j = 0; j < HID; ++j) acc[j] = 0.0f;
  for (int k = 0; k < F_IN; k += 16) {
    float4 a0 = *reinterpret_cast<const float4*>(xr + k);
    float4 a1 = *reinterpret_cast<const float4*>(xr + k + 4);
    float4 a2 = *reinterpret_cast<const float4*>(xr + k + 8);
    float4 a3 = *reinterpret_cast<const float4*>(xr + k + 12);
    float xv[16] = {a0.x, a0.y, a0.z, a0.w, a1.x, a1.y, a1.z, a1.w,
                    a2.x, a2.y, a2.z, a2.w, a3.x, a3.y, a3.z, a3.w};
#pragma unroll
    for (int kk = 0; kk < 16; ++kk) {
      float xx = xv[kk];
      const float* wr = W1 + (size_t)(k + kk) * HID;
#pragma unroll
      for (int j = 0; j < HID; ++j) acc[j] = fmaf(xx, wr[j], acc[j]);
    }
  }
  float di = dis[n];
  uint4 w0, w1;
  w0.x = pack2(acc[0] * di,  acc[1] * di);  w0.y = pack2(acc[2] * di,  acc[3] * di);
  w0.z = pack2(acc[4] * di,  acc[5] * di);  w0.w = pack2(acc[6] * di,  acc[7] * di);
  w1.x = pack2(acc[8] * di,  acc[9] * di);  w1.y = pack2(acc[10] * di, acc[11] * di);
  w1.z = pack2(acc[12] * di, acc[13] * di); w1.w = pack2(acc[14] * di, acc[15] * di);
  hb1[(size_t)n * 2]     = w0;
  hb1[(size_t)n * 2 + 1] = w1;
}

// ---- aggregation: ONE NODE PER LANE, 16 f32 register accumulators, zero LDS.
//      LAYER1: hb2 = bf16( relu((acc+self)*dis+b1)*dis )   LAYER2: g = (acc+self)*dis ----
template <int LAYER>
__global__ void __launch_bounds__(256)
k_aggn(const uint2* __restrict__ payload, const int* __restrict__ rs,
       const uint4* __restrict__ hb, const float* __restrict__ dis,
       const float* __restrict__ b1, uint4* __restrict__ hb2,
       float* __restrict__ g, int N) {
  int n = blockIdx.x * 256 + threadIdx.x;
  if (n >= N) return;
  int e0 = rs[n], e1 = rs[n + 1];
  float a0 = 0, a1 = 0, a2 = 0, a3 = 0, a4 = 0, a5 = 0, a6 = 0, a7 = 0;
  float a8 = 0, a9 = 0, a10 = 0, a11 = 0, a12 = 0, a13 = 0, a14 = 0, a15 = 0;
#pragma unroll 2
  for (int e = e0; e < e1; ++e) {
    uint2 p = payload[e];
    const uint4* row = hb + ((size_t)p.x * 2);
    uint4 r0 = row[0];
    uint4 r1 = row[1];
    float w = __uint_as_float(p.y);
    a0  = fmaf(blo(r0.x), w, a0);  a1  = fmaf(bhi(r0.x), w, a1);
    a2  = fmaf(blo(r0.y), w, a2);  a3  = fmaf(bhi(r0.y), w, a3);
    a4  = fmaf(blo(r0.z), w, a4);  a5  = fmaf(bhi(r0.z), w, a5);
    a6  = fmaf(blo(r0.w), w, a6);  a7  = fmaf(bhi(r0.w), w, a7);
    a8  = fmaf(blo(r1.x), w, a8);  a9  = fmaf(bhi(r1.x), w, a9);
    a10 = fmaf(blo(r1.y), w, a10); a11 = fmaf(bhi(r1.y), w, a11);
    a12 = fmaf(blo(r1.z), w, a12); a13 = fmaf(bhi(r1.z), w, a13);
    a14 = fmaf(blo(r1.w), w, a14); a15 = fmaf(bhi(r1.w), w, a15);
  }
  uint4 s0 = hb[(size_t)n * 2];
  uint4 s1 = hb[(size_t)n * 2 + 1];
  float di = dis[n];
  a0  = (a0  + blo(s0.x)) * di;  a1  = (a1  + bhi(s0.x)) * di;
  a2  = (a2  + blo(s0.y)) * di;  a3  = (a3  + bhi(s0.y)) * di;
  a4  = (a4  + blo(s0.z)) * di;  a5  = (a5  + bhi(s0.z)) * di;
  a6  = (a6  + blo(s0.w)) * di;  a7  = (a7  + bhi(s0.w)) * di;
  a8  = (a8  + blo(s1.x)) * di;  a9  = (a9  + bhi(s1.x)) * di;
  a10 = (a10 + blo(s1.y)) * di;  a11 = (a11 + bhi(s1.y)) * di;
  a12 = (a12 + blo(s1.z)) * di;  a13 = (a13 + bhi(s1.z)) * di;
  a14 = (a14 + blo(s1.w)) * di;  a15 = (a15 + bhi(s1.w)) * di;
  if (LAYER == 1) {
    a0  = fmaxf(a0  + b1[0],  0.0f) * di;  a1  = fmaxf(a1  + b1[1],  0.0f) * di;
    a2  = fmaxf(a2  + b1[2],  0.0f) * di;  a3  = fmaxf(a3  + b1[3],  0.0f) * di;
    a4  = fmaxf(a4  + b1[4],  0.0f) * di;  a5  = fmaxf(a5  + b1[5],  0.0f) * di;
    a6  = fmaxf(a6  + b1[6],  0.0f) * di;  a7  = fmaxf(a7  + b1[7],  0.0f) * di;
    a8  = fmaxf(a8  + b1[8],  0.0f) * di;  a9  = fmaxf(a9  + b1[9],  0.0f) * di;
    a10 = fmaxf(a10 + b1[10], 0.0f) * di;  a11 = fmaxf(a11 + b1[11], 0.0f) * di;
    a12 = fmaxf(a12 + b1[12], 0.0f) * di;  a13 = fmaxf(a13 + b1[13], 0.0f) * di;
    a14 = fmaxf(a14 + b1[14], 0.0f) * di;  a15 = fmaxf(a15 + b1[15], 0.0f) * di;
    uint4 w0, w1;
    w0.x = pack2(a0,  a1);  w0.y = pack2(a2,  a3);
    w0.z = pack2(a4,  a5);  w0.w = pack2(a6,  a7);
    w1.x = pack2(a8,  a9);  w1.y = pack2(a10, a11);
    w1.z = pack2(a12, a13); w1.w = pack2(a14, a15);
    hb2[(size_t)n * 2]     = w0;
    hb2[(size_t)n * 2 + 1] = w1;
  } else {
    float4* gr = reinterpret_cast<float4*>(g + (size_t)n * HID);
    gr[0] = make_float4(a0,  a1,  a2,  a3);
    gr[1] = make_float4(a4,  a5,  a6,  a7);
    gr[2] = make_float4(a8,  a9,  a10, a11);
    gr[3] = make_float4(a12, a13, a14, a15);
  }
}

// ---- out = log_softmax(g @ W2 + b2), thread-per-node ----
__global__ void k_out(const float* __restrict__ g, const float* __restrict__ W2,
                      const float* __restrict__ b2, float* __restrict__ out, int N) {
  int n = blockIdx.x * blockDim.x + threadIdx.x;
  if (n >= N) return;
  float gv[HID];
#pragma unroll
  for (int j = 0; j < HID; ++j) gv[j] = g[(size_t)n * HID + j];
  float o[NCLS];
#pragma unroll
  for (int c = 0; c < NCLS; ++c) o[c] = b2[c];
#pragma unroll
  for (int j = 0; j < HID; ++j) {
    float gj = gv[j];
    const float* wr = W2 + (size_t)j * NCLS;
#pragma unroll
    for (int c = 0; c < NCLS; ++c) o[c] = fmaf(gj, wr[c], o[c]);
  }
  float m = o[0];
#pragma unroll
  for (int c = 1; c < NCLS; ++c) m = fmaxf(m, o[c]);
  float ss = 0.0f;
#pragma unroll
  for (int c = 0; c < NCLS; ++c) ss += expf(o[c] - m);
  float lse = m + logf(ss);
  float* orow = out + (size_t)n * NCLS;
#pragma unroll
  for (int c = 0; c < NCLS; ++c) orow[c] = o[c] - lse;
}

extern "C" void kernel_launch(void* const* d_in, const int* in_sizes, int n_in,
                              void* d_out, int out_size, void* d_ws, size_t ws_size,
                              hipStream_t stream) {
  const float* x  = (const float*)d_in[0];
  const int*   ei = (const int*)d_in[1];
  const float* ew = (const float*)d_in[2];
  const float* W1 = (const float*)d_in[3];
  const float* b1 = (const float*)d_in[4];
  const float* W2 = (const float*)d_in[5];
  const float* b2 = (const float*)d_in[6];
  float* out = (float*)d_out;

  const int N = in_sizes[0] / F_IN;   // 100000
  const int E = in_sizes[2];          // 3200000
  const int* src = ei;
  const int* dst = ei + E;

  const int NB    = (N + 127) >> 7;            // 782 buckets (<= BMAX)
  const int NBLK  = (E + CHUNK - 1) / CHUNK;   // 782 chunks
  const int NBLKp = (NBLK + 31) & ~31;         // 800
  const long long SCT = (long long)NB * NBLKp + 1;
  const int Npad  = (int)((SCT + 1023) & ~1023LL);
  const int nbScan = Npad / 1024;
  const int Nr    = (NB * 128 + 256 + 255) & ~255;  // rs/dis region (covers NB*128+1)

  // ws layout (4B words):
  // counts[Npad] | bsum[1024] | dis[Nr] | rs[Nr] | hb1[N*8] | hb2[N*8] | g[N*16] | payload[2E]
  int* counts = (int*)d_ws;
  int* bsum   = counts + Npad;
  float* dis  = (float*)(bsum + 1024);
  int* rs     = (int*)(dis + Nr);
  uint4* hb1  = (uint4*)(rs + Nr);
  uint4* hb2  = hb1 + (size_t)N * 2;
  float* g    = (float*)(hb2 + (size_t)N * 2);
  uint2* payload = (uint2*)(g + (size_t)N * HID);

  hipMemsetAsync(counts, 0, (size_t)Npad * sizeof(int), stream);
  k_count<<<NBLK, 256, 0, stream>>>(dst, counts, E, NB, NBLKp);
  k_scanA<<<nbScan, 256, 0, stream>>>(counts, bsum);
  k_scanB<<<1, 1024, 0, stream>>>(bsum, nbScan);
  k_scanC<<<nbScan, 256, 0, stream>>>(counts, bsum);
  k_scatter<<<NBLK, 256, 0, stream>>>(src, dst, ew, counts, payload, E, NB, NBLKp);
  k_sortb<<<NB, 256, 0, stream>>>(payload, counts, rs, dis, N, NBLKp);
  k_gemm1<<<(N + 255) / 256, 256, 0, stream>>>(x, W1, dis, hb1, N);
  k_aggn<1><<<(N + 255) / 256, 256, 0, stream>>>(payload, rs, hb1, dis, b1, hb2, nullptr, N);
  k_aggn<2><<<(N + 255) / 256, 256, 0, stream>>>(payload, rs, hb2, dis, nullptr, nullptr, g, N);
  k_out<<<(N + 255) / 256, 256, 0, stream>>>(g, W2, b2, out, N);
}